// Round 3
// baseline (823.719 us; speedup 1.0000x reference)
//
#include <hip/hip_runtime.h>
#include <stdint.h>

#define BN   1024
#define FEATN 512
#define HDIM 256
#define TAUF 5.0f
#define EPSF 1e-8f

typedef __attribute__((ext_vector_type(8))) _Float16 half8;
typedef __attribute__((ext_vector_type(4))) float f32x4;

#if defined(__has_builtin)
#if __has_builtin(__builtin_amdgcn_rcpf)
#define HAVE_RCPF 1
#endif
#endif

#ifdef HAVE_RCPF
__device__ __forceinline__ float fast_rcp(float x) { return __builtin_amdgcn_rcpf(x); }
#else
__device__ __forceinline__ float fast_rcp(float x) { return 1.0f / x; }
#endif

// tanh-approx gelu == x * sigmoid(1.5957691x + 0.0713548x^3)
__device__ __forceinline__ float gelu_fast(float x) {
  float s = fmaf(x * x, 0.07135481627f, 1.59576912161f) * x;
  float e = __expf(s);
  return x * e * fast_rcp(e + 1.0f);
}

// ---------------- prep: W1[:512] -> fp16 frag order; label softmax ----------------
__global__ __launch_bounds__(256) void prep_kernel(const float* __restrict__ W1,
                                                   const float* __restrict__ lg,
                                                   _Float16* __restrict__ w1h,
                                                   float* __restrict__ oh) {
  int b = blockIdx.x, t = threadIdx.x;
  if (b < FEATN) {
    int k = b, n = t;
    // B-frag layout: element (k,n) at ((k>>3)*256 + n)*8 + (k&7)
    w1h[(((k >> 3) * HDIM) + n) * 8 + (k & 7)] = (_Float16)W1[k * HDIM + n];
  } else {
    int i = (b - FEATN) * 256 + t;
    float l0 = lg[2 * i], l1 = lg[2 * i + 1];
    float m = fmaxf(l0, l1);
    float e0 = __expf(l0 - m), e1 = __expf(l1 - m);
    float inv = 1.0f / (e0 + e1);
    oh[2 * i] = e0 * inv;
    oh[2 * i + 1] = e1 * inv;
  }
}

// ---------------- main: fused pair-GEMM (fp16 MFMA) + gelu + W2-dot + sigmoid ----------------
// h_scores is SYMMETRIC -> lower-triangle tiles only (grid 65x128 rectangle folded),
// each block writes its 8x8 tile AND the shfl-transposed mirror tile.
// Round-3 change (isolated): LDS 34.8 KB -> 25.3 KB => 6 blocks/CU instead of 4.
//   - sX staged one K-half (256 elems) at a time; half 1 re-staged at the t=3 seam
//   - sScore aliases the dead sX buffer in the epilogue
// Everything else identical to the verified 184 us round-1 kernel.
__global__ __launch_bounds__(256, 6) void gemm_kernel(const float* __restrict__ X,
                                                      const _Float16* __restrict__ w1h,
                                                      const float* __restrict__ oh,
                                                      const float* __restrict__ W1,
                                                      const float* __restrict__ b1,
                                                      const float* __restrict__ W2,
                                                      const float* __restrict__ b2,
                                                      float* __restrict__ out_hs) {
  __shared__ __align__(16) _Float16 sXh[16 * 264];    // 8448 B: rows 0-7: i, 8-15: j (one K-half)
  __shared__ __align__(16) half8 sA[2][2][4][64];     // 16 KB [buf][step-in-chunk][m-subtile][lane]
  __shared__ float sLab0[64], sLab1[64];
  float* sScore = (float*)sXh;                        // 1 KB, alias: sXh dead after CONSTRUCT kt=15

  const int tid = threadIdx.x;
  const int L = tid & 63;
  const int w = tid >> 6;              // wave id == n-quarter AND construct m-subtile

  // triangle fold: map grid (x in [0,65), y in [0,128)) onto lower-tri tiles (bi >= bj).
  int bi = blockIdx.y, bj = blockIdx.x;
  if (bj > bi) { bi = 127 - bi; bj = 128 - bj; }
  const int i0 = bi * 8;
  const int j0 = bj * 8;

  // ---- stage one K-half of 16 X rows, f32 -> fp16 (RTNE), LDS stride 264 fp16 ----
  #define STAGE(h)                                                        \
    {                                                                     \
      _Pragma("unroll")                                                   \
      for (int it = 0; it < 2; ++it) {                                    \
        int idx = tid + it * 256;      /* 512 octet tasks (16 rows x 32 octets) */ \
        int row = idx >> 5;                                               \
        int oc = idx & 31;                                                \
        int grow = (row < 8) ? (i0 + row) : (j0 + row - 8);               \
        const float* gp = X + grow * FEATN + (h) * 256 + oc * 8;          \
        float4 a = *(const float4*)gp;                                    \
        float4 c = *(const float4*)(gp + 4);                              \
        half8 hv;                                                         \
        hv[0] = (_Float16)a.x; hv[1] = (_Float16)a.y;                     \
        hv[2] = (_Float16)a.z; hv[3] = (_Float16)a.w;                     \
        hv[4] = (_Float16)c.x; hv[5] = (_Float16)c.y;                     \
        hv[6] = (_Float16)c.z; hv[7] = (_Float16)c.w;                     \
        *(half8*)(sXh + row * 264 + oc * 8) = hv;                         \
      }                                                                   \
    }

  STAGE(0)
  if (tid < 64) {
    int gi = i0 + (tid >> 3), gj = j0 + (tid & 7);
    sLab0[tid] = oh[2 * gi] * oh[2 * gj];
    sLab1[tid] = oh[2 * gi + 1] * oh[2 * gj + 1];
  }

  // ---- construct decode: wave w builds m-subtile w's frag for lane L ----
  // pair m = 16w + (L&15); ii = 2w + ((L&15)>>3); jj = L&7; koct = L>>4
  const int nl = L & 15;
  const int koct = L >> 4;
  const _Float16* cxi = sXh + (2 * w + (nl >> 3)) * 264 + koct * 8;
  const _Float16* cxj = sXh + (8 + (L & 7)) * 264 + koct * 8;

  // B-frag per-lane base (fp16 elems): global step kt at +kt*8192, n-subtile u at +u*128
  const _Float16* bbase = w1h + ((koct * HDIM) + w * 64 + nl) * 8;

  f32x4 acc[4][4];
  #pragma unroll
  for (int s = 0; s < 4; ++s)
    #pragma unroll
    for (int u = 0; u < 4; ++u) acc[s][u] = (f32x4){0.f, 0.f, 0.f, 0.f};

  __syncthreads();

  // construct step's A-frag from staged half; ktl = kt & 7 (offset within half)
  #define CONSTRUCT(ktl, buf, st)                                         \
    {                                                                     \
      half8 xi = *(const half8*)(cxi + (ktl) * 32);                       \
      half8 xj = *(const half8*)(cxj + (ktl) * 32);                       \
      union { half8 h; unsigned u4[4]; } U;                               \
      U.h = xi - xj;                                                      \
      U.u4[0] &= 0x7FFF7FFFu; U.u4[1] &= 0x7FFF7FFFu;                     \
      U.u4[2] &= 0x7FFF7FFFu; U.u4[3] &= 0x7FFF7FFFu;                     \
      sA[buf][st][w][L] = U.h;                                            \
    }

  #define CONSUME(kt, buf, st)                                            \
    {                                                                     \
      half8 afr[4];                                                       \
      _Pragma("unroll")                                                   \
      for (int s = 0; s < 4; ++s) afr[s] = sA[buf][st][s][L];             \
      half8 bfr[4];                                                       \
      _Pragma("unroll")                                                   \
      for (int u = 0; u < 4; ++u)                                         \
        bfr[u] = *(const half8*)(bbase + (kt) * 8192 + u * 128);          \
      _Pragma("unroll")                                                   \
      for (int s = 0; s < 4; ++s)                                         \
        _Pragma("unroll")                                                 \
        for (int u = 0; u < 4; ++u)                                       \
          acc[s][u] = __builtin_amdgcn_mfma_f32_16x16x32_f16(             \
              afr[s], bfr[u], acc[s][u], 0, 0, 0);                        \
    }

  // prologue: chunk 0 (global steps 0,1)
  CONSTRUCT(0, 0, 0)
  CONSTRUCT(1, 0, 1)
  __syncthreads();

  // t=0..2 (half 0; buf = t&1)
  CONSUME(0, 0, 0)  CONSUME(1, 0, 1)  CONSTRUCT(2, 1, 0) CONSTRUCT(3, 1, 1) __syncthreads();
  CONSUME(2, 1, 0)  CONSUME(3, 1, 1)  CONSTRUCT(4, 0, 0) CONSTRUCT(5, 0, 1) __syncthreads();
  CONSUME(4, 0, 0)  CONSUME(5, 0, 1)  CONSTRUCT(6, 1, 0) CONSTRUCT(7, 1, 1) __syncthreads();
  // t=3: K-half seam. All waves are past CONSTRUCT(7) (last half-0 read) due to the
  // barrier above, so sXh can be overwritten. Stage loads overlap CONSUME(6,7) MFMAs.
  STAGE(1)
  CONSUME(6, 1, 0)  CONSUME(7, 1, 1)
  __syncthreads();                     // staged half 1 visible
  CONSTRUCT(0, 0, 0) CONSTRUCT(1, 0, 1)   // global steps 8,9
  __syncthreads();
  // t=4..6 (half 1)
  CONSUME(8, 0, 0)  CONSUME(9, 0, 1)  CONSTRUCT(2, 1, 0) CONSTRUCT(3, 1, 1) __syncthreads();
  CONSUME(10, 1, 0) CONSUME(11, 1, 1) CONSTRUCT(4, 0, 0) CONSTRUCT(5, 0, 1) __syncthreads();
  CONSUME(12, 0, 0) CONSUME(13, 0, 1) CONSTRUCT(6, 1, 0) CONSTRUCT(7, 1, 1) __syncthreads();
  // t=7
  CONSUME(14, 1, 0) CONSUME(15, 1, 1)
  __syncthreads();
  #undef CONSTRUCT
  #undef CONSUME
  #undef STAGE

  // ---- epilogue: + label rank-2 + b1, fast gelu, dot W2, reduce, sigmoid ----
  const int q = L >> 4;
  float w1l0[4], w1l1[4], bb1[4], ww2[4];
  #pragma unroll
  for (int u = 0; u < 4; ++u) {
    int n = w * 64 + u * 16 + nl;
    w1l0[u] = W1[512 * HDIM + n];
    w1l1[u] = W1[513 * HDIM + n];
    bb1[u] = b1[n];
    ww2[u] = W2[n];
  }
  #pragma unroll
  for (int s = 0; s < 4; ++s) {
    #pragma unroll
    for (int r = 0; r < 4; ++r) {
      int m = s * 16 + q * 4 + r;     // C/D: row = quad*4 + reg
      float l0v = sLab0[m], l1v = sLab1[m];
      float v = 0.f;
      #pragma unroll
      for (int u = 0; u < 4; ++u) {
        float e = acc[s][u][r] + l0v * w1l0[u] + l1v * w1l1[u] + bb1[u];
        v += gelu_fast(e) * ww2[u];
      }
      v += __shfl_xor(v, 1, 64);
      v += __shfl_xor(v, 2, 64);
      v += __shfl_xor(v, 4, 64);
      v += __shfl_xor(v, 8, 64);       // sum over 16 lanes of the quad
      if (nl == 0) sScore[m * 4 + w] = v;
    }
  }
  __syncthreads();
  if (tid < 64) {
    float s4 = sScore[tid * 4 + 0] + sScore[tid * 4 + 1] + sScore[tid * 4 + 2] +
               sScore[tid * 4 + 3] + b2[0];
    float hsv = fast_rcp(1.0f + __expf(-s4));
    int r = tid >> 3, c = tid & 7;
    out_hs[(size_t)(i0 + r) * BN + (j0 + c)] = hsv;
    if (i0 != j0) {
      // mirror tile: element (j0+r, i0+c) = hsv of pair (i0+c, j0+r) = lane (c*8+r)
      float tv = __shfl(hsv, (c << 3) | r, 64);
      out_hs[(size_t)(j0 + r) * BN + (i0 + c)] = tv;
    }
  }
}

// ---------------- row softmax of adj + TAU*log(hs + EPS) ----------------
__global__ __launch_bounds__(256) void softmax_kernel(const float* __restrict__ adj,
                                                      const float* __restrict__ hs,
                                                      float* __restrict__ out) {
  int i = blockIdx.x, t = threadIdx.x;
  __shared__ float redm[4];
  __shared__ float reds[4];
  float l[4];
  float mx = -1e30f;
  #pragma unroll
  for (int k = 0; k < 4; ++k) {
    int j = t + k * 256;
    float lv = adj[(size_t)i * BN + j] + TAUF * __logf(hs[(size_t)i * BN + j] + EPSF);
    l[k] = lv;
    mx = fmaxf(mx, lv);
  }
  #pragma unroll
  for (int o = 1; o <= 32; o <<= 1) mx = fmaxf(mx, __shfl_xor(mx, o, 64));
  if ((t & 63) == 0) redm[t >> 6] = mx;
  __syncthreads();
  mx = fmaxf(fmaxf(redm[0], redm[1]), fmaxf(redm[2], redm[3]));
  float ex[4];
  float se = 0.f;
  #pragma unroll
  for (int k = 0; k < 4; ++k) { ex[k] = __expf(l[k] - mx); se += ex[k]; }
  #pragma unroll
  for (int o = 1; o <= 32; o <<= 1) se += __shfl_xor(se, o, 64);
  if ((t & 63) == 0) reds[t >> 6] = se;
  __syncthreads();
  se = reds[0] + reds[1] + reds[2] + reds[3];
  float inv = fast_rcp(se);
  #pragma unroll
  for (int k = 0; k < 4; ++k) out[(size_t)i * BN + t + k * 256] = ex[k] * inv;
}

extern "C" void kernel_launch(void* const* d_in, const int* in_sizes, int n_in,
                              void* d_out, int out_size, void* d_ws, size_t ws_size,
                              hipStream_t stream) {
  (void)in_sizes; (void)n_in; (void)out_size; (void)ws_size;
  const float* X   = (const float*)d_in[0];
  const float* lg  = (const float*)d_in[1];
  const float* adj = (const float*)d_in[2];
  const float* W1  = (const float*)d_in[3];
  const float* b1  = (const float*)d_in[4];
  const float* W2  = (const float*)d_in[5];
  const float* b2  = (const float*)d_in[6];
  float* out = (float*)d_out;                       // [0,B^2): adj_refined, [B^2,2B^2): h_scores
  _Float16* w1h = (_Float16*)d_ws;                  // 512*256 fp16 = 256 KB
  float* oh = (float*)((char*)d_ws + FEATN * HDIM * 2);  // 1024*2 f32

  float* out_hs = out + (size_t)BN * BN;

  prep_kernel<<<dim3(FEATN + 4), dim3(256), 0, stream>>>(W1, lg, w1h, oh);
  // lower-triangle tiles only (h_scores is symmetric): 65x128 rectangle folds onto triangle
  gemm_kernel<<<dim3(65, 128), dim3(256), 0, stream>>>(X, w1h, oh, W1, b1, W2, b2, out_hs);
  softmax_kernel<<<dim3(BN), dim3(256), 0, stream>>>(adj, out_hs, out);
}

// Round 4
// 250.901 us; speedup vs baseline: 3.2830x; 3.2830x over previous
//
#include <hip/hip_runtime.h>
#include <stdint.h>

#define BN   1024
#define FEATN 512
#define HDIM 256
#define TAUF 5.0f
#define EPSF 1e-8f

typedef __attribute__((ext_vector_type(8))) _Float16 half8;
typedef __attribute__((ext_vector_type(4))) float f32x4;

#if defined(__has_builtin)
#if __has_builtin(__builtin_amdgcn_rcpf)
#define HAVE_RCPF 1
#endif
#endif

#ifdef HAVE_RCPF
__device__ __forceinline__ float fast_rcp(float x) { return __builtin_amdgcn_rcpf(x); }
#else
__device__ __forceinline__ float fast_rcp(float x) { return 1.0f / x; }
#endif

// tanh-approx gelu == x * sigmoid(1.5957691x + 0.0713548x^3)
__device__ __forceinline__ float gelu_fast(float x) {
  float s = fmaf(x * x, 0.07135481627f, 1.59576912161f) * x;
  float e = __expf(s);
  return x * e * fast_rcp(e + 1.0f);
}

// ---------------- prep: W1[:512] -> fp16 frag order; label softmax ----------------
__global__ __launch_bounds__(256) void prep_kernel(const float* __restrict__ W1,
                                                   const float* __restrict__ lg,
                                                   _Float16* __restrict__ w1h,
                                                   float* __restrict__ oh) {
  int b = blockIdx.x, t = threadIdx.x;
  if (b < FEATN) {
    int k = b, n = t;
    // B-frag layout: element (k,n) at ((k>>3)*256 + n)*8 + (k&7)
    w1h[(((k >> 3) * HDIM) + n) * 8 + (k & 7)] = (_Float16)W1[k * HDIM + n];
  } else {
    int i = (b - FEATN) * 256 + t;
    float l0 = lg[2 * i], l1 = lg[2 * i + 1];
    float m = fmaxf(l0, l1);
    float e0 = __expf(l0 - m), e1 = __expf(l1 - m);
    float inv = 1.0f / (e0 + e1);
    oh[2 * i] = e0 * inv;
    oh[2 * i + 1] = e1 * inv;
  }
}

// ---------------- main: fused pair-GEMM (fp16 MFMA) + gelu + W2-dot + sigmoid ----------------
// h_scores is SYMMETRIC -> lower-triangle tiles only (grid 65x128 rectangle folded),
// each block writes its 8x8 tile AND the shfl-transposed mirror tile.
// LDS 25.6 KB => HW fits 6 blocks/CU. launch_bounds stays (256,4): round-3's (256,6)
// capped VGPRs at ~85 and spilled the 64-reg accumulator to scratch (FETCH 10MB->1GB,
// WRITE 4MB->2.3GB, 794us). VGPR=56 allows 9 waves/SIMD; LDS is the real limiter.
__global__ __launch_bounds__(256, 4) void gemm_kernel(const float* __restrict__ X,
                                                      const _Float16* __restrict__ w1h,
                                                      const float* __restrict__ oh,
                                                      const float* __restrict__ W1,
                                                      const float* __restrict__ b1,
                                                      const float* __restrict__ W2,
                                                      const float* __restrict__ b2,
                                                      float* __restrict__ out_hs) {
  __shared__ __align__(16) _Float16 sXh[16 * 264];    // 8448 B: rows 0-7: i, 8-15: j (one K-half)
  __shared__ __align__(16) half8 sA[2][2][4][64];     // 16 KB [buf][step-in-chunk][m-subtile][lane]
  __shared__ float sLab0[64], sLab1[64];
  float* sScore = (float*)sXh;                        // 1 KB, alias: sXh dead after last CONSTRUCT

  const int tid = threadIdx.x;
  const int L = tid & 63;
  const int w = tid >> 6;              // wave id == n-quarter AND construct m-subtile

  // triangle fold: map grid (x in [0,65), y in [0,128)) onto lower-tri tiles (bi >= bj).
  int bi = blockIdx.y, bj = blockIdx.x;
  if (bj > bi) { bi = 127 - bi; bj = 128 - bj; }
  const int i0 = bi * 8;
  const int j0 = bj * 8;

  // ---- stage one K-half of 16 X rows, f32 -> fp16 (RTNE), LDS stride 264 fp16 ----
  #define STAGE(h)                                                        \
    {                                                                     \
      _Pragma("unroll")                                                   \
      for (int it = 0; it < 2; ++it) {                                    \
        int idx = tid + it * 256;      /* 512 octet tasks (16 rows x 32 octets) */ \
        int row = idx >> 5;                                               \
        int oc = idx & 31;                                                \
        int grow = (row < 8) ? (i0 + row) : (j0 + row - 8);               \
        const float* gp = X + grow * FEATN + (h) * 256 + oc * 8;          \
        float4 a = *(const float4*)gp;                                    \
        float4 c = *(const float4*)(gp + 4);                              \
        half8 hv;                                                         \
        hv[0] = (_Float16)a.x; hv[1] = (_Float16)a.y;                     \
        hv[2] = (_Float16)a.z; hv[3] = (_Float16)a.w;                     \
        hv[4] = (_Float16)c.x; hv[5] = (_Float16)c.y;                     \
        hv[6] = (_Float16)c.z; hv[7] = (_Float16)c.w;                     \
        *(half8*)(sXh + row * 264 + oc * 8) = hv;                         \
      }                                                                   \
    }

  STAGE(0)
  if (tid < 64) {
    int gi = i0 + (tid >> 3), gj = j0 + (tid & 7);
    sLab0[tid] = oh[2 * gi] * oh[2 * gj];
    sLab1[tid] = oh[2 * gi + 1] * oh[2 * gj + 1];
  }

  // ---- construct decode: wave w builds m-subtile w's frag for lane L ----
  // pair m = 16w + (L&15); ii = 2w + ((L&15)>>3); jj = L&7; koct = L>>4
  const int nl = L & 15;
  const int koct = L >> 4;
  const _Float16* cxi = sXh + (2 * w + (nl >> 3)) * 264 + koct * 8;
  const _Float16* cxj = sXh + (8 + (L & 7)) * 264 + koct * 8;

  // B-frag per-lane base (fp16 elems): global step kt at +kt*8192, n-subtile u at +u*128
  const _Float16* bbase = w1h + ((koct * HDIM) + w * 64 + nl) * 8;

  f32x4 acc[4][4];
  #pragma unroll
  for (int s = 0; s < 4; ++s)
    #pragma unroll
    for (int u = 0; u < 4; ++u) acc[s][u] = (f32x4){0.f, 0.f, 0.f, 0.f};

  __syncthreads();

  // construct step's A-frag from staged half; ktl = kt & 7 (offset within half)
  #define CONSTRUCT(ktl, buf, st)                                         \
    {                                                                     \
      half8 xi = *(const half8*)(cxi + (ktl) * 32);                       \
      half8 xj = *(const half8*)(cxj + (ktl) * 32);                       \
      union { half8 h; unsigned u4[4]; } U;                               \
      U.h = xi - xj;                                                      \
      U.u4[0] &= 0x7FFF7FFFu; U.u4[1] &= 0x7FFF7FFFu;                     \
      U.u4[2] &= 0x7FFF7FFFu; U.u4[3] &= 0x7FFF7FFFu;                     \
      sA[buf][st][w][L] = U.h;                                            \
    }

  #define CONSUME(kt, buf, st)                                            \
    {                                                                     \
      half8 afr[4];                                                       \
      _Pragma("unroll")                                                   \
      for (int s = 0; s < 4; ++s) afr[s] = sA[buf][st][s][L];             \
      half8 bfr[4];                                                       \
      _Pragma("unroll")                                                   \
      for (int u = 0; u < 4; ++u)                                         \
        bfr[u] = *(const half8*)(bbase + (kt) * 8192 + u * 128);          \
      _Pragma("unroll")                                                   \
      for (int s = 0; s < 4; ++s)                                         \
        _Pragma("unroll")                                                 \
        for (int u = 0; u < 4; ++u)                                       \
          acc[s][u] = __builtin_amdgcn_mfma_f32_16x16x32_f16(             \
              afr[s], bfr[u], acc[s][u], 0, 0, 0);                        \
    }

  // prologue: chunk 0 (global steps 0,1)
  CONSTRUCT(0, 0, 0)
  CONSTRUCT(1, 0, 1)
  __syncthreads();

  // t=0..2 (half 0; buf = t&1)
  CONSUME(0, 0, 0)  CONSUME(1, 0, 1)  CONSTRUCT(2, 1, 0) CONSTRUCT(3, 1, 1) __syncthreads();
  CONSUME(2, 1, 0)  CONSUME(3, 1, 1)  CONSTRUCT(4, 0, 0) CONSTRUCT(5, 0, 1) __syncthreads();
  CONSUME(4, 0, 0)  CONSUME(5, 0, 1)  CONSTRUCT(6, 1, 0) CONSTRUCT(7, 1, 1) __syncthreads();
  // t=3: K-half seam. All waves are past CONSTRUCT(7) (last half-0 read) due to the
  // barrier above, so sXh can be overwritten. Stage loads overlap CONSUME(6,7) MFMAs.
  STAGE(1)
  CONSUME(6, 1, 0)  CONSUME(7, 1, 1)
  __syncthreads();                     // staged half 1 visible
  CONSTRUCT(0, 0, 0) CONSTRUCT(1, 0, 1)   // global steps 8,9
  __syncthreads();
  // t=4..6 (half 1)
  CONSUME(8, 0, 0)  CONSUME(9, 0, 1)  CONSTRUCT(2, 1, 0) CONSTRUCT(3, 1, 1) __syncthreads();
  CONSUME(10, 1, 0) CONSUME(11, 1, 1) CONSTRUCT(4, 0, 0) CONSTRUCT(5, 0, 1) __syncthreads();
  CONSUME(12, 0, 0) CONSUME(13, 0, 1) CONSTRUCT(6, 1, 0) CONSTRUCT(7, 1, 1) __syncthreads();
  // t=7
  CONSUME(14, 1, 0) CONSUME(15, 1, 1)
  __syncthreads();
  #undef CONSTRUCT
  #undef CONSUME
  #undef STAGE

  // ---- epilogue: + label rank-2 + b1, fast gelu, dot W2, reduce, sigmoid ----
  const int q = L >> 4;
  float w1l0[4], w1l1[4], bb1[4], ww2[4];
  #pragma unroll
  for (int u = 0; u < 4; ++u) {
    int n = w * 64 + u * 16 + nl;
    w1l0[u] = W1[512 * HDIM + n];
    w1l1[u] = W1[513 * HDIM + n];
    bb1[u] = b1[n];
    ww2[u] = W2[n];
  }
  #pragma unroll
  for (int s = 0; s < 4; ++s) {
    #pragma unroll
    for (int r = 0; r < 4; ++r) {
      int m = s * 16 + q * 4 + r;     // C/D: row = quad*4 + reg
      float l0v = sLab0[m], l1v = sLab1[m];
      float v = 0.f;
      #pragma unroll
      for (int u = 0; u < 4; ++u) {
        float e = acc[s][u][r] + l0v * w1l0[u] + l1v * w1l1[u] + bb1[u];
        v += gelu_fast(e) * ww2[u];
      }
      v += __shfl_xor(v, 1, 64);
      v += __shfl_xor(v, 2, 64);
      v += __shfl_xor(v, 4, 64);
      v += __shfl_xor(v, 8, 64);       // sum over 16 lanes of the quad
      if (nl == 0) sScore[m * 4 + w] = v;
    }
  }
  __syncthreads();
  if (tid < 64) {
    float s4 = sScore[tid * 4 + 0] + sScore[tid * 4 + 1] + sScore[tid * 4 + 2] +
               sScore[tid * 4 + 3] + b2[0];
    float hsv = fast_rcp(1.0f + __expf(-s4));
    int r = tid >> 3, c = tid & 7;
    out_hs[(size_t)(i0 + r) * BN + (j0 + c)] = hsv;
    if (i0 != j0) {
      // mirror tile: element (j0+r, i0+c) = hsv of pair (i0+c, j0+r) = lane (c*8+r)
      float tv = __shfl(hsv, (c << 3) | r, 64);
      out_hs[(size_t)(j0 + r) * BN + (i0 + c)] = tv;
    }
  }
}

// ---------------- row softmax of adj + TAU*log(hs + EPS) ----------------
__global__ __launch_bounds__(256) void softmax_kernel(const float* __restrict__ adj,
                                                      const float* __restrict__ hs,
                                                      float* __restrict__ out) {
  int i = blockIdx.x, t = threadIdx.x;
  __shared__ float redm[4];
  __shared__ float reds[4];
  float l[4];
  float mx = -1e30f;
  #pragma unroll
  for (int k = 0; k < 4; ++k) {
    int j = t + k * 256;
    float lv = adj[(size_t)i * BN + j] + TAUF * __logf(hs[(size_t)i * BN + j] + EPSF);
    l[k] = lv;
    mx = fmaxf(mx, lv);
  }
  #pragma unroll
  for (int o = 1; o <= 32; o <<= 1) mx = fmaxf(mx, __shfl_xor(mx, o, 64));
  if ((t & 63) == 0) redm[t >> 6] = mx;
  __syncthreads();
  mx = fmaxf(fmaxf(redm[0], redm[1]), fmaxf(redm[2], redm[3]));
  float ex[4];
  float se = 0.f;
  #pragma unroll
  for (int k = 0; k < 4; ++k) { ex[k] = __expf(l[k] - mx); se += ex[k]; }
  #pragma unroll
  for (int o = 1; o <= 32; o <<= 1) se += __shfl_xor(se, o, 64);
  if ((t & 63) == 0) reds[t >> 6] = se;
  __syncthreads();
  se = reds[0] + reds[1] + reds[2] + reds[3];
  float inv = fast_rcp(se);
  #pragma unroll
  for (int k = 0; k < 4; ++k) out[(size_t)i * BN + t + k * 256] = ex[k] * inv;
}

extern "C" void kernel_launch(void* const* d_in, const int* in_sizes, int n_in,
                              void* d_out, int out_size, void* d_ws, size_t ws_size,
                              hipStream_t stream) {
  (void)in_sizes; (void)n_in; (void)out_size; (void)ws_size;
  const float* X   = (const float*)d_in[0];
  const float* lg  = (const float*)d_in[1];
  const float* adj = (const float*)d_in[2];
  const float* W1  = (const float*)d_in[3];
  const float* b1  = (const float*)d_in[4];
  const float* W2  = (const float*)d_in[5];
  const float* b2  = (const float*)d_in[6];
  float* out = (float*)d_out;                       // [0,B^2): adj_refined, [B^2,2B^2): h_scores
  _Float16* w1h = (_Float16*)d_ws;                  // 512*256 fp16 = 256 KB
  float* oh = (float*)((char*)d_ws + FEATN * HDIM * 2);  // 1024*2 f32

  float* out_hs = out + (size_t)BN * BN;

  prep_kernel<<<dim3(FEATN + 4), dim3(256), 0, stream>>>(W1, lg, w1h, oh);
  // lower-triangle tiles only (h_scores is symmetric): 65x128 rectangle folds onto triangle
  gemm_kernel<<<dim3(65, 128), dim3(256), 0, stream>>>(X, w1h, oh, W1, b1, W2, b2, out_hs);
  softmax_kernel<<<dim3(BN), dim3(256), 0, stream>>>(adj, out_hs, out);
}

// Round 5
// 250.369 us; speedup vs baseline: 3.2900x; 1.0021x over previous
//
#include <hip/hip_runtime.h>
#include <stdint.h>

#define BN   1024
#define FEATN 512
#define HDIM 256
#define TAUF 5.0f
#define EPSF 1e-8f

typedef __attribute__((ext_vector_type(8))) _Float16 half8;
typedef __attribute__((ext_vector_type(4))) float f32x4;

#if defined(__has_builtin)
#if __has_builtin(__builtin_amdgcn_rcpf)
#define HAVE_RCPF 1
#endif
#endif

#ifdef HAVE_RCPF
__device__ __forceinline__ float fast_rcp(float x) { return __builtin_amdgcn_rcpf(x); }
#else
__device__ __forceinline__ float fast_rcp(float x) { return 1.0f / x; }
#endif

// tanh-approx gelu == x * sigmoid(1.5957691x + 0.0713548x^3)
__device__ __forceinline__ float gelu_fast(float x) {
  float s = fmaf(x * x, 0.07135481627f, 1.59576912161f) * x;
  float e = __expf(s);
  return x * e * fast_rcp(e + 1.0f);
}

// lgkm-only barrier: all cross-wave hazards in gemm are LDS (sX, sA, sScore), covered
// by lgkmcnt(0). __syncthreads() would additionally drain vmcnt(0), killing B-frag
// load pipelining across k-steps (B loads are read-only global: no cross-wave hazard).
#define BAR() asm volatile("s_waitcnt lgkmcnt(0)\n\ts_barrier" ::: "memory")

// ---------------- prep: W1[:512] -> fp16 frag order; label softmax ----------------
__global__ __launch_bounds__(256) void prep_kernel(const float* __restrict__ W1,
                                                   const float* __restrict__ lg,
                                                   _Float16* __restrict__ w1h,
                                                   float* __restrict__ oh) {
  int b = blockIdx.x, t = threadIdx.x;
  if (b < FEATN) {
    int k = b, n = t;
    // B-frag layout: element (k,n) at ((k>>3)*256 + n)*8 + (k&7)
    w1h[(((k >> 3) * HDIM) + n) * 8 + (k & 7)] = (_Float16)W1[k * HDIM + n];
  } else {
    int i = (b - FEATN) * 256 + t;
    float l0 = lg[2 * i], l1 = lg[2 * i + 1];
    float m = fmaxf(l0, l1);
    float e0 = __expf(l0 - m), e1 = __expf(l1 - m);
    float inv = 1.0f / (e0 + e1);
    oh[2 * i] = e0 * inv;
    oh[2 * i + 1] = e1 * inv;
  }
}

// ---------------- main: fused pair-GEMM (fp16 MFMA) + gelu + W2-dot + sigmoid ----------------
// h_scores is SYMMETRIC -> lower-triangle tiles only (grid 65x128 rectangle folded),
// each block writes its 8x8 tile AND the shfl-transposed mirror tile.
// Structure = round-1 champion (184 us). Round-5 isolated change: K-loop barriers are
// lgkm-only (BAR) so B-frag L2 loads stay in flight across barriers.
// NOTE: occupancy is register-limited (64 VGPR + 64 AGPR acc = 128/lane -> 4 waves/SIMD);
// LDS (34.8 KB) is NOT the limiter, so sX stays full-K. launch_bounds (256,4): asking
// for more spills the accumulator (round-3: FETCH 10MB -> 1GB, 794 us).
__global__ __launch_bounds__(256, 4) void gemm_kernel(const float* __restrict__ X,
                                                      const _Float16* __restrict__ w1h,
                                                      const float* __restrict__ oh,
                                                      const float* __restrict__ W1,
                                                      const float* __restrict__ b1,
                                                      const float* __restrict__ W2,
                                                      const float* __restrict__ b2,
                                                      float* __restrict__ out_hs) {
  __shared__ __align__(16) _Float16 sX[16 * 520];     // rows 0-7: i, 8-15: j (stride 520 fp16)
  __shared__ __align__(16) half8 sA[2][2][4][64];     // [buf][step-in-chunk][m-subtile][lane]
  __shared__ float sScore[64 * 4];
  __shared__ float sLab0[64], sLab1[64];

  const int tid = threadIdx.x;
  const int L = tid & 63;
  const int w = tid >> 6;              // wave id == n-quarter AND construct m-subtile

  // triangle fold: map grid (x in [0,65), y in [0,128)) onto lower-tri tiles (bi >= bj).
  int bi = blockIdx.y, bj = blockIdx.x;
  if (bj > bi) { bi = 127 - bi; bj = 128 - bj; }
  const int i0 = bi * 8;
  const int j0 = bj * 8;

  // ---- stage 16 X rows, f32 -> fp16 (RTNE), LDS stride 520 fp16 ----
  #pragma unroll
  for (int it = 0; it < 4; ++it) {
    int idx = tid + it * 256;          // 1024 octet tasks (16 rows x 64 octets)
    int row = idx >> 6;
    int oc = idx & 63;
    int grow = (row < 8) ? (i0 + row) : (j0 + row - 8);
    const float* gp = X + grow * FEATN + oc * 8;
    float4 a = *(const float4*)gp;
    float4 c = *(const float4*)(gp + 4);
    half8 hv;
    hv[0] = (_Float16)a.x; hv[1] = (_Float16)a.y; hv[2] = (_Float16)a.z; hv[3] = (_Float16)a.w;
    hv[4] = (_Float16)c.x; hv[5] = (_Float16)c.y; hv[6] = (_Float16)c.z; hv[7] = (_Float16)c.w;
    *(half8*)(sX + row * 520 + oc * 8) = hv;
  }
  if (tid < 64) {
    int gi = i0 + (tid >> 3), gj = j0 + (tid & 7);
    sLab0[tid] = oh[2 * gi] * oh[2 * gj];
    sLab1[tid] = oh[2 * gi + 1] * oh[2 * gj + 1];
  }

  // ---- construct decode: wave w builds m-subtile w's frag for lane L ----
  // pair m = 16w + (L&15); ii = 2w + ((L&15)>>3); jj = L&7; koct = L>>4
  const int nl = L & 15;
  const int koct = L >> 4;
  const _Float16* cxi = sX + (2 * w + (nl >> 3)) * 520 + koct * 8;
  const _Float16* cxj = sX + (8 + (L & 7)) * 520 + koct * 8;

  // B-frag per-lane base (fp16 elems): step kt at +kt*8192, n-subtile u at +u*128
  const _Float16* bbase = w1h + ((koct * HDIM) + w * 64 + nl) * 8;

  f32x4 acc[4][4];
  #pragma unroll
  for (int s = 0; s < 4; ++s)
    #pragma unroll
    for (int u = 0; u < 4; ++u) acc[s][u] = (f32x4){0.f, 0.f, 0.f, 0.f};

  BAR();

  // construct one step's A-frag (fp16 pk-sub + abs mask) into sA[buf][st]
  #define CONSTRUCT(kt, buf, st)                                          \
    {                                                                     \
      half8 xi = *(const half8*)(cxi + (kt) * 32);                        \
      half8 xj = *(const half8*)(cxj + (kt) * 32);                        \
      union { half8 h; unsigned u4[4]; } U;                               \
      U.h = xi - xj;                                                      \
      U.u4[0] &= 0x7FFF7FFFu; U.u4[1] &= 0x7FFF7FFFu;                     \
      U.u4[2] &= 0x7FFF7FFFu; U.u4[3] &= 0x7FFF7FFFu;                     \
      sA[buf][st][w][L] = U.h;                                            \
    }

  #define CONSUME(kt, buf, st)                                            \
    {                                                                     \
      half8 afr[4];                                                       \
      _Pragma("unroll")                                                   \
      for (int s = 0; s < 4; ++s) afr[s] = sA[buf][st][s][L];             \
      half8 bfr[4];                                                       \
      _Pragma("unroll")                                                   \
      for (int u = 0; u < 4; ++u)                                         \
        bfr[u] = *(const half8*)(bbase + (kt) * 8192 + u * 128);          \
      _Pragma("unroll")                                                   \
      for (int s = 0; s < 4; ++s)                                         \
        _Pragma("unroll")                                                 \
        for (int u = 0; u < 4; ++u)                                       \
          acc[s][u] = __builtin_amdgcn_mfma_f32_16x16x32_f16(             \
              afr[s], bfr[u], acc[s][u], 0, 0, 0);                        \
    }

  // prologue: chunk 0 (steps 0,1)
  CONSTRUCT(0, 0, 0)
  CONSTRUCT(1, 0, 1)
  BAR();

  #pragma unroll 2
  for (int t = 0; t < 8; ++t) {
    const int buf = t & 1;
    CONSUME(2 * t, buf, 0)
    CONSUME(2 * t + 1, buf, 1)
    if (t < 7) {
      CONSTRUCT(2 * t + 2, 1 - buf, 0)
      CONSTRUCT(2 * t + 3, 1 - buf, 1)
    }
    BAR();
  }
  #undef CONSTRUCT
  #undef CONSUME

  // ---- epilogue: + label rank-2 + b1, fast gelu, dot W2, reduce, sigmoid ----
  const int q = L >> 4;
  float w1l0[4], w1l1[4], bb1[4], ww2[4];
  #pragma unroll
  for (int u = 0; u < 4; ++u) {
    int n = w * 64 + u * 16 + nl;
    w1l0[u] = W1[512 * HDIM + n];
    w1l1[u] = W1[513 * HDIM + n];
    bb1[u] = b1[n];
    ww2[u] = W2[n];
  }
  #pragma unroll
  for (int s = 0; s < 4; ++s) {
    #pragma unroll
    for (int r = 0; r < 4; ++r) {
      int m = s * 16 + q * 4 + r;     // C/D: row = quad*4 + reg
      float l0v = sLab0[m], l1v = sLab1[m];
      float v = 0.f;
      #pragma unroll
      for (int u = 0; u < 4; ++u) {
        float e = acc[s][u][r] + l0v * w1l0[u] + l1v * w1l1[u] + bb1[u];
        v += gelu_fast(e) * ww2[u];
      }
      v += __shfl_xor(v, 1, 64);
      v += __shfl_xor(v, 2, 64);
      v += __shfl_xor(v, 4, 64);
      v += __shfl_xor(v, 8, 64);       // sum over 16 lanes of the quad
      if (nl == 0) sScore[m * 4 + w] = v;
    }
  }
  BAR();
  if (tid < 64) {
    float s4 = sScore[tid * 4 + 0] + sScore[tid * 4 + 1] + sScore[tid * 4 + 2] +
               sScore[tid * 4 + 3] + b2[0];
    float hsv = fast_rcp(1.0f + __expf(-s4));
    int r = tid >> 3, c = tid & 7;
    out_hs[(size_t)(i0 + r) * BN + (j0 + c)] = hsv;
    if (i0 != j0) {
      // mirror tile: element (j0+r, i0+c) = hsv of pair (i0+c, j0+r) = lane (c*8+r)
      float tv = __shfl(hsv, (c << 3) | r, 64);
      out_hs[(size_t)(j0 + r) * BN + (i0 + c)] = tv;
    }
  }
}

// ---------------- row softmax of adj + TAU*log(hs + EPS) ----------------
__global__ __launch_bounds__(256) void softmax_kernel(const float* __restrict__ adj,
                                                      const float* __restrict__ hs,
                                                      float* __restrict__ out) {
  int i = blockIdx.x, t = threadIdx.x;
  __shared__ float redm[4];
  __shared__ float reds[4];
  float l[4];
  float mx = -1e30f;
  #pragma unroll
  for (int k = 0; k < 4; ++k) {
    int j = t + k * 256;
    float lv = adj[(size_t)i * BN + j] + TAUF * __logf(hs[(size_t)i * BN + j] + EPSF);
    l[k] = lv;
    mx = fmaxf(mx, lv);
  }
  #pragma unroll
  for (int o = 1; o <= 32; o <<= 1) mx = fmaxf(mx, __shfl_xor(mx, o, 64));
  if ((t & 63) == 0) redm[t >> 6] = mx;
  __syncthreads();
  mx = fmaxf(fmaxf(redm[0], redm[1]), fmaxf(redm[2], redm[3]));
  float ex[4];
  float se = 0.f;
  #pragma unroll
  for (int k = 0; k < 4; ++k) { ex[k] = __expf(l[k] - mx); se += ex[k]; }
  #pragma unroll
  for (int o = 1; o <= 32; o <<= 1) se += __shfl_xor(se, o, 64);
  if ((t & 63) == 0) reds[t >> 6] = se;
  __syncthreads();
  se = reds[0] + reds[1] + reds[2] + reds[3];
  float inv = fast_rcp(se);
  #pragma unroll
  for (int k = 0; k < 4; ++k) out[(size_t)i * BN + t + k * 256] = ex[k] * inv;
}

extern "C" void kernel_launch(void* const* d_in, const int* in_sizes, int n_in,
                              void* d_out, int out_size, void* d_ws, size_t ws_size,
                              hipStream_t stream) {
  (void)in_sizes; (void)n_in; (void)out_size; (void)ws_size;
  const float* X   = (const float*)d_in[0];
  const float* lg  = (const float*)d_in[1];
  const float* adj = (const float*)d_in[2];
  const float* W1  = (const float*)d_in[3];
  const float* b1  = (const float*)d_in[4];
  const float* W2  = (const float*)d_in[5];
  const float* b2  = (const float*)d_in[6];
  float* out = (float*)d_out;                       // [0,B^2): adj_refined, [B^2,2B^2): h_scores
  _Float16* w1h = (_Float16*)d_ws;                  // 512*256 fp16 = 256 KB
  float* oh = (float*)((char*)d_ws + FEATN * HDIM * 2);  // 1024*2 f32

  float* out_hs = out + (size_t)BN * BN;

  prep_kernel<<<dim3(FEATN + 4), dim3(256), 0, stream>>>(W1, lg, w1h, oh);
  // lower-triangle tiles only (h_scores is symmetric): 65x128 rectangle folds onto triangle
  gemm_kernel<<<dim3(65, 128), dim3(256), 0, stream>>>(X, w1h, oh, W1, b1, W2, b2, out_hs);
  softmax_kernel<<<dim3(BN), dim3(256), 0, stream>>>(adj, out_hs, out);
}

// Round 6
// 241.655 us; speedup vs baseline: 3.4087x; 1.0361x over previous
//
#include <hip/hip_runtime.h>
#include <stdint.h>

#define BN   1024
#define FEATN 512
#define HDIM 256
#define TAUF 5.0f
#define EPSF 1e-8f

typedef __attribute__((ext_vector_type(8))) _Float16 half8;
typedef __attribute__((ext_vector_type(4))) float f32x4;

#if defined(__has_builtin)
#if __has_builtin(__builtin_amdgcn_rcpf)
#define HAVE_RCPF 1
#endif
#endif

#ifdef HAVE_RCPF
__device__ __forceinline__ float fast_rcp(float x) { return __builtin_amdgcn_rcpf(x); }
#else
__device__ __forceinline__ float fast_rcp(float x) { return 1.0f / x; }
#endif

// tanh-approx gelu == x * sigmoid(1.5957691x + 0.0713548x^3)
__device__ __forceinline__ float gelu_fast(float x) {
  float s = fmaf(x * x, 0.07135481627f, 1.59576912161f) * x;
  float e = __expf(s);
  return x * e * fast_rcp(e + 1.0f);
}

// lgkm-only barrier: all cross-wave hazards in gemm are LDS (sX, sA, sScore), covered
// by lgkmcnt(0). Measured neutral vs __syncthreads (r5) but never worse; keep.
#define BAR() asm volatile("s_waitcnt lgkmcnt(0)\n\ts_barrier" ::: "memory")

// ---------------- prep: W1[:512] + 17th step -> fp16 frag order; label softmax ----------------
__global__ __launch_bounds__(256) void prep_kernel(const float* __restrict__ W1,
                                                   const float* __restrict__ b1,
                                                   const float* __restrict__ lg,
                                                   _Float16* __restrict__ w1h,
                                                   float* __restrict__ oh) {
  int b = blockIdx.x, t = threadIdx.x;
  if (b < FEATN) {
    int k = b, n = t;
    // B-frag layout: element (k,n) at ((k>>3)*256 + n)*8 + (k&7)
    w1h[(((k >> 3) * HDIM) + n) * 8 + (k & 7)] = (_Float16)W1[k * HDIM + n];
  } else if (b < FEATN + 4) {
    int i = (b - FEATN) * 256 + t;
    float l0 = lg[2 * i], l1 = lg[2 * i + 1];
    float m = fmaxf(l0, l1);
    float e0 = __expf(l0 - m), e1 = __expf(l1 - m);
    float inv = 1.0f / (e0 + e1);
    oh[2 * i] = e0 * inv;
    oh[2 * i + 1] = e1 * inv;
  } else {
    // 17th B-step (kt=16): virtual K-rows {W1[512], W1[513], b1, 0...} for the
    // rank-2-label + bias fold. Same frag layout, koct = b - FEATN - 4.
    int koct = b - FEATN - 4;
    half8 hv = (half8){};
    if (koct == 0) {
      hv[0] = (_Float16)W1[512 * HDIM + t];
      hv[1] = (_Float16)W1[513 * HDIM + t];
      hv[2] = (_Float16)b1[t];
    }
    *(half8*)(w1h + 16 * 8192 + (koct * HDIM + t) * 8) = hv;
  }
}

// ---------------- main: fused pair-GEMM (fp16 MFMA) + gelu + W2-dot + sigmoid ----------------
// h_scores is SYMMETRIC -> lower-triangle tiles only (grid 65x128 rectangle folded),
// each block writes its 8x8 tile AND the shfl-transposed mirror tile.
// Round-6 isolated change: label rank-2 + b1 folded into a 17th MFMA k-step
// (A: {lab0[m], lab1[m], 1.0, 0...}; B: {W1[512], W1[513], b1, 0...}), removing
// 3 FMA x 64 elems/thread from the VALU-dominated epilogue (VALUBusy 64%).
// NOTE: occupancy is register-limited (64 VGPR + 64 AGPR acc = 128/lane -> 4 waves/SIMD).
// launch_bounds must stay (256,4): (256,6) spilled the accumulator (round-3, 794 us).
__global__ __launch_bounds__(256, 4) void gemm_kernel(const float* __restrict__ X,
                                                      const _Float16* __restrict__ w1h,
                                                      const float* __restrict__ oh,
                                                      const float* __restrict__ W2,
                                                      const float* __restrict__ b2,
                                                      float* __restrict__ out_hs) {
  __shared__ __align__(16) _Float16 sX[16 * 520];     // rows 0-7: i, 8-15: j (stride 520 fp16)
  __shared__ __align__(16) half8 sA[2][2][4][64];     // [buf][step-in-chunk][m-subtile][lane]
  __shared__ float sScore[64 * 4];
  __shared__ float sLab0[64], sLab1[64];

  const int tid = threadIdx.x;
  const int L = tid & 63;
  const int w = tid >> 6;              // wave id == n-quarter AND construct m-subtile

  // triangle fold: map grid (x in [0,65), y in [0,128)) onto lower-tri tiles (bi >= bj).
  int bi = blockIdx.y, bj = blockIdx.x;
  if (bj > bi) { bi = 127 - bi; bj = 128 - bj; }
  const int i0 = bi * 8;
  const int j0 = bj * 8;

  // ---- stage 16 X rows, f32 -> fp16 (RTNE), LDS stride 520 fp16 ----
  #pragma unroll
  for (int it = 0; it < 4; ++it) {
    int idx = tid + it * 256;          // 1024 octet tasks (16 rows x 64 octets)
    int row = idx >> 6;
    int oc = idx & 63;
    int grow = (row < 8) ? (i0 + row) : (j0 + row - 8);
    const float* gp = X + grow * FEATN + oc * 8;
    float4 a = *(const float4*)gp;
    float4 c = *(const float4*)(gp + 4);
    half8 hv;
    hv[0] = (_Float16)a.x; hv[1] = (_Float16)a.y; hv[2] = (_Float16)a.z; hv[3] = (_Float16)a.w;
    hv[4] = (_Float16)c.x; hv[5] = (_Float16)c.y; hv[6] = (_Float16)c.z; hv[7] = (_Float16)c.w;
    *(half8*)(sX + row * 520 + oc * 8) = hv;
  }
  if (tid < 64) {
    int gi = i0 + (tid >> 3), gj = j0 + (tid & 7);
    sLab0[tid] = oh[2 * gi] * oh[2 * gj];
    sLab1[tid] = oh[2 * gi + 1] * oh[2 * gj + 1];
  }

  // ---- construct decode: wave w builds m-subtile w's frag for lane L ----
  // pair m = 16w + (L&15); ii = 2w + ((L&15)>>3); jj = L&7; koct = L>>4
  const int nl = L & 15;
  const int koct = L >> 4;
  const _Float16* cxi = sX + (2 * w + (nl >> 3)) * 520 + koct * 8;
  const _Float16* cxj = sX + (8 + (L & 7)) * 520 + koct * 8;

  // B-frag per-lane base (fp16 elems): step kt at +kt*8192, n-subtile u at +u*128
  const _Float16* bbase = w1h + ((koct * HDIM) + w * 64 + nl) * 8;

  f32x4 acc[4][4];
  #pragma unroll
  for (int s = 0; s < 4; ++s)
    #pragma unroll
    for (int u = 0; u < 4; ++u) acc[s][u] = (f32x4){0.f, 0.f, 0.f, 0.f};

  BAR();

  // construct one step's A-frag (fp16 pk-sub + abs mask) into sA[buf][st]
  #define CONSTRUCT(kt, buf, st)                                          \
    {                                                                     \
      half8 xi = *(const half8*)(cxi + (kt) * 32);                        \
      half8 xj = *(const half8*)(cxj + (kt) * 32);                        \
      union { half8 h; unsigned u4[4]; } U;                               \
      U.h = xi - xj;                                                      \
      U.u4[0] &= 0x7FFF7FFFu; U.u4[1] &= 0x7FFF7FFFu;                     \
      U.u4[2] &= 0x7FFF7FFFu; U.u4[3] &= 0x7FFF7FFFu;                     \
      sA[buf][st][w][L] = U.h;                                            \
    }

  #define CONSUME(kt, buf, st)                                            \
    {                                                                     \
      half8 afr[4];                                                       \
      _Pragma("unroll")                                                   \
      for (int s = 0; s < 4; ++s) afr[s] = sA[buf][st][s][L];             \
      half8 bfr[4];                                                       \
      _Pragma("unroll")                                                   \
      for (int u = 0; u < 4; ++u)                                         \
        bfr[u] = *(const half8*)(bbase + (kt) * 8192 + u * 128);          \
      _Pragma("unroll")                                                   \
      for (int s = 0; s < 4; ++s)                                         \
        _Pragma("unroll")                                                 \
        for (int u = 0; u < 4; ++u)                                       \
          acc[s][u] = __builtin_amdgcn_mfma_f32_16x16x32_f16(             \
              afr[s], bfr[u], acc[s][u], 0, 0, 0);                        \
    }

  // prologue: chunk 0 (steps 0,1)
  CONSTRUCT(0, 0, 0)
  CONSTRUCT(1, 0, 1)
  BAR();

  #pragma unroll 2
  for (int t = 0; t < 8; ++t) {
    const int buf = t & 1;
    CONSUME(2 * t, buf, 0)
    CONSUME(2 * t + 1, buf, 1)
    if (t < 7) {
      CONSTRUCT(2 * t + 2, 1 - buf, 0)
      CONSTRUCT(2 * t + 3, 1 - buf, 1)
    }
    BAR();
  }
  #undef CONSTRUCT
  #undef CONSUME

  // ---- 17th k-step: label rank-2 + bias via MFMA ----
  // A[m][512..514] = {lab0[m], lab1[m], 1.0}, zeros elsewhere (koct!=0 lanes all-zero).
  {
    half8 bfr[4];
    #pragma unroll
    for (int u = 0; u < 4; ++u)
      bfr[u] = *(const half8*)(bbase + 16 * 8192 + u * 128);
    #pragma unroll
    for (int s = 0; s < 4; ++s) {
      half8 af = (half8){};
      if (koct == 0) {
        int m = s * 16 + nl;
        af[0] = (_Float16)sLab0[m];
        af[1] = (_Float16)sLab1[m];
        af[2] = (_Float16)1.0f;
      }
      #pragma unroll
      for (int u = 0; u < 4; ++u)
        acc[s][u] = __builtin_amdgcn_mfma_f32_16x16x32_f16(af, bfr[u], acc[s][u], 0, 0, 0);
    }
  }

  // ---- epilogue: fast gelu, dot W2, reduce, sigmoid ----
  const int q = L >> 4;
  float ww2[4];
  #pragma unroll
  for (int u = 0; u < 4; ++u) ww2[u] = W2[w * 64 + u * 16 + nl];
  #pragma unroll
  for (int s = 0; s < 4; ++s) {
    #pragma unroll
    for (int r = 0; r < 4; ++r) {
      int m = s * 16 + q * 4 + r;     // C/D: row = quad*4 + reg
      float v = 0.f;
      #pragma unroll
      for (int u = 0; u < 4; ++u) v += gelu_fast(acc[s][u][r]) * ww2[u];
      v += __shfl_xor(v, 1, 64);
      v += __shfl_xor(v, 2, 64);
      v += __shfl_xor(v, 4, 64);
      v += __shfl_xor(v, 8, 64);       // sum over 16 lanes of the quad
      if (nl == 0) sScore[m * 4 + w] = v;
    }
  }
  BAR();
  if (tid < 64) {
    float s4 = sScore[tid * 4 + 0] + sScore[tid * 4 + 1] + sScore[tid * 4 + 2] +
               sScore[tid * 4 + 3] + b2[0];
    float hsv = fast_rcp(1.0f + __expf(-s4));
    int r = tid >> 3, c = tid & 7;
    out_hs[(size_t)(i0 + r) * BN + (j0 + c)] = hsv;
    if (i0 != j0) {
      // mirror tile: element (j0+r, i0+c) = hsv of pair (i0+c, j0+r) = lane (c*8+r)
      float tv = __shfl(hsv, (c << 3) | r, 64);
      out_hs[(size_t)(j0 + r) * BN + (i0 + c)] = tv;
    }
  }
}

// ---------------- row softmax of adj + TAU*log(hs + EPS) ----------------
__global__ __launch_bounds__(256) void softmax_kernel(const float* __restrict__ adj,
                                                      const float* __restrict__ hs,
                                                      float* __restrict__ out) {
  int i = blockIdx.x, t = threadIdx.x;
  __shared__ float redm[4];
  __shared__ float reds[4];
  float l[4];
  float mx = -1e30f;
  #pragma unroll
  for (int k = 0; k < 4; ++k) {
    int j = t + k * 256;
    float lv = adj[(size_t)i * BN + j] + TAUF * __logf(hs[(size_t)i * BN + j] + EPSF);
    l[k] = lv;
    mx = fmaxf(mx, lv);
  }
  #pragma unroll
  for (int o = 1; o <= 32; o <<= 1) mx = fmaxf(mx, __shfl_xor(mx, o, 64));
  if ((t & 63) == 0) redm[t >> 6] = mx;
  __syncthreads();
  mx = fmaxf(fmaxf(redm[0], redm[1]), fmaxf(redm[2], redm[3]));
  float ex[4];
  float se = 0.f;
  #pragma unroll
  for (int k = 0; k < 4; ++k) { ex[k] = __expf(l[k] - mx); se += ex[k]; }
  #pragma unroll
  for (int o = 1; o <= 32; o <<= 1) se += __shfl_xor(se, o, 64);
  if ((t & 63) == 0) reds[t >> 6] = se;
  __syncthreads();
  se = reds[0] + reds[1] + reds[2] + reds[3];
  float inv = fast_rcp(se);
  #pragma unroll
  for (int k = 0; k < 4; ++k) out[(size_t)i * BN + t + k * 256] = ex[k] * inv;
}

extern "C" void kernel_launch(void* const* d_in, const int* in_sizes, int n_in,
                              void* d_out, int out_size, void* d_ws, size_t ws_size,
                              hipStream_t stream) {
  (void)in_sizes; (void)n_in; (void)out_size; (void)ws_size;
  const float* X   = (const float*)d_in[0];
  const float* lg  = (const float*)d_in[1];
  const float* adj = (const float*)d_in[2];
  const float* W1  = (const float*)d_in[3];
  const float* b1  = (const float*)d_in[4];
  const float* W2  = (const float*)d_in[5];
  const float* b2  = (const float*)d_in[6];
  float* out = (float*)d_out;                       // [0,B^2): adj_refined, [B^2,2B^2): h_scores
  _Float16* w1h = (_Float16*)d_ws;                  // 17*8192 fp16 = 272 KB (16 steps + label/bias step)
  float* oh = (float*)((char*)d_ws + 17 * 8192 * 2);  // 1024*2 f32

  float* out_hs = out + (size_t)BN * BN;

  prep_kernel<<<dim3(FEATN + 8), dim3(256), 0, stream>>>(W1, b1, lg, w1h, oh);
  // lower-triangle tiles only (h_scores is symmetric): 65x128 rectangle folds onto triangle
  gemm_kernel<<<dim3(65, 128), dim3(256), 0, stream>>>(X, w1h, oh, W2, b2, out_hs);
  softmax_kernel<<<dim3(BN), dim3(256), 0, stream>>>(adj, out_hs, out);
}

// Round 7
// 237.555 us; speedup vs baseline: 3.4675x; 1.0173x over previous
//
#include <hip/hip_runtime.h>
#include <stdint.h>

#define BN   1024
#define FEATN 512
#define HDIM 256
#define TAUF 5.0f
#define EPSF 1e-8f

typedef __attribute__((ext_vector_type(8))) _Float16 half8;
typedef __attribute__((ext_vector_type(4))) float f32x4;

#if defined(__has_builtin)
#if __has_builtin(__builtin_amdgcn_rcpf)
#define HAVE_RCPF 1
#endif
#if __has_builtin(__builtin_amdgcn_exp2f)
#define HAVE_EXP2F 1
#endif
#endif

#ifdef HAVE_RCPF
__device__ __forceinline__ float fast_rcp(float x) { return __builtin_amdgcn_rcpf(x); }
#else
__device__ __forceinline__ float fast_rcp(float x) { return 1.0f / x; }
#endif

#ifdef HAVE_EXP2F
__device__ __forceinline__ float fast_exp2(float x) { return __builtin_amdgcn_exp2f(x); }
#else
__device__ __forceinline__ float fast_exp2(float x) { return exp2f(x); }
#endif

// gelu(x)*w2 via tanh-approx == x*w2*sigmoid(1.5957691x + 0.0713548x^3).
// log2e folded into the poly constants; sigmoid as 1/(1+2^q), q = -s*log2e.
#define GC1 (-0.102944544f)   // -0.07135481627 * log2(e)
#define GC2 (-2.302116228f)   // -1.59576912161 * log2(e)
__device__ __forceinline__ float gelu_w2_acc(float x, float w2, float v) {
  float t = x * x;
  float p = fmaf(t, GC1, GC2);
  float q = p * x;                  // q = -s*log2e
  float e = fast_exp2(q);
  float r = fast_rcp(e + 1.0f);     // sigmoid(s)
  return fmaf(x * w2, r, v);
}

// lgkm-only barrier: all cross-wave hazards in gemm are LDS (sX, sA, sScore), covered
// by lgkmcnt(0). Measured neutral vs __syncthreads (r5) but never worse; keep.
#define BAR() asm volatile("s_waitcnt lgkmcnt(0)\n\ts_barrier" ::: "memory")

// ---------------- prep: W1[:512] + 17th step -> fp16 frag order; label softmax ----------------
__global__ __launch_bounds__(256) void prep_kernel(const float* __restrict__ W1,
                                                   const float* __restrict__ b1,
                                                   const float* __restrict__ lg,
                                                   _Float16* __restrict__ w1h,
                                                   float* __restrict__ oh) {
  int b = blockIdx.x, t = threadIdx.x;
  if (b < FEATN) {
    int k = b, n = t;
    // B-frag layout: element (k,n) at ((k>>3)*256 + n)*8 + (k&7)
    w1h[(((k >> 3) * HDIM) + n) * 8 + (k & 7)] = (_Float16)W1[k * HDIM + n];
  } else if (b < FEATN + 4) {
    int i = (b - FEATN) * 256 + t;
    float l0 = lg[2 * i], l1 = lg[2 * i + 1];
    float m = fmaxf(l0, l1);
    float e0 = __expf(l0 - m), e1 = __expf(l1 - m);
    float inv = 1.0f / (e0 + e1);
    oh[2 * i] = e0 * inv;
    oh[2 * i + 1] = e1 * inv;
  } else {
    // 17th B-step (kt=16): virtual K-rows {W1[512], W1[513], b1, 0...} for the
    // rank-2-label + bias fold. Same frag layout, koct = b - FEATN - 4.
    int koct = b - FEATN - 4;
    half8 hv = (half8){};
    if (koct == 0) {
      hv[0] = (_Float16)W1[512 * HDIM + t];
      hv[1] = (_Float16)W1[513 * HDIM + t];
      hv[2] = (_Float16)b1[t];
    }
    *(half8*)(w1h + 16 * 8192 + (koct * HDIM + t) * 8) = hv;
  }
}

// ---------------- main: fused pair-GEMM (fp16 MFMA) + gelu + W2-dot + sigmoid ----------------
// h_scores is SYMMETRIC -> lower-triangle tiles only (grid 65x128 rectangle folded),
// each block writes its 8x8 tile AND the shfl-transposed mirror tile.
// Round-7 isolated changes (all VALU-side; max pipe = VALU 57%):
//   - gelu epilogue: 10 -> 8 ops/elem (log2e folded, sigmoid-form, w2 premul)
//   - step-0 CONSUME peeled with C=0 literal (kills 64 accvgpr zero-inits)
// REGISTER DISCIPLINE: 64 VGPR + 64 AGPR acc = exactly 128/lane = 4 waves/SIMD.
// Any +8 VGPR drops to 3 waves/SIMD (-25% occupancy). launch_bounds must stay
// (256,4): (256,6) spilled the accumulator (round-3: 794 us, FETCH 10MB->1GB).
__global__ __launch_bounds__(256, 4) void gemm_kernel(const float* __restrict__ X,
                                                      const _Float16* __restrict__ w1h,
                                                      const float* __restrict__ oh,
                                                      const float* __restrict__ W2,
                                                      const float* __restrict__ b2,
                                                      float* __restrict__ out_hs) {
  __shared__ __align__(16) _Float16 sX[16 * 520];     // rows 0-7: i, 8-15: j (stride 520 fp16)
  __shared__ __align__(16) half8 sA[2][2][4][64];     // [buf][step-in-chunk][m-subtile][lane]
  __shared__ float sScore[64 * 4];
  __shared__ float sLab0[64], sLab1[64];

  const int tid = threadIdx.x;
  const int L = tid & 63;
  const int w = tid >> 6;              // wave id == n-quarter AND construct m-subtile

  // triangle fold: map grid (x in [0,65), y in [0,128)) onto lower-tri tiles (bi >= bj).
  int bi = blockIdx.y, bj = blockIdx.x;
  if (bj > bi) { bi = 127 - bi; bj = 128 - bj; }
  const int i0 = bi * 8;
  const int j0 = bj * 8;

  // ---- stage 16 X rows, f32 -> fp16 (RTNE), LDS stride 520 fp16 ----
  #pragma unroll
  for (int it = 0; it < 4; ++it) {
    int idx = tid + it * 256;          // 1024 octet tasks (16 rows x 64 octets)
    int row = idx >> 6;
    int oc = idx & 63;
    int grow = (row < 8) ? (i0 + row) : (j0 + row - 8);
    const float* gp = X + grow * FEATN + oc * 8;
    float4 a = *(const float4*)gp;
    float4 c = *(const float4*)(gp + 4);
    half8 hv;
    hv[0] = (_Float16)a.x; hv[1] = (_Float16)a.y; hv[2] = (_Float16)a.z; hv[3] = (_Float16)a.w;
    hv[4] = (_Float16)c.x; hv[5] = (_Float16)c.y; hv[6] = (_Float16)c.z; hv[7] = (_Float16)c.w;
    *(half8*)(sX + row * 520 + oc * 8) = hv;
  }
  if (tid < 64) {
    int gi = i0 + (tid >> 3), gj = j0 + (tid & 7);
    sLab0[tid] = oh[2 * gi] * oh[2 * gj];
    sLab1[tid] = oh[2 * gi + 1] * oh[2 * gj + 1];
  }

  // ---- construct decode: wave w builds m-subtile w's frag for lane L ----
  // pair m = 16w + (L&15); ii = 2w + ((L&15)>>3); jj = L&7; koct = L>>4
  const int nl = L & 15;
  const int koct = L >> 4;
  const _Float16* cxi = sX + (2 * w + (nl >> 3)) * 520 + koct * 8;
  const _Float16* cxj = sX + (8 + (L & 7)) * 520 + koct * 8;

  // B-frag per-lane base (fp16 elems): step kt at +kt*8192, n-subtile u at +u*128
  const _Float16* bbase = w1h + ((koct * HDIM) + w * 64 + nl) * 8;

  f32x4 acc[4][4];                     // written first by CONSUME0 (no zero-init)

  BAR();

  // construct one step's A-frag (fp16 pk-sub + abs mask) into sA[buf][st]
  #define CONSTRUCT(kt, buf, st)                                          \
    {                                                                     \
      half8 xi = *(const half8*)(cxi + (kt) * 32);                        \
      half8 xj = *(const half8*)(cxj + (kt) * 32);                        \
      union { half8 h; unsigned u4[4]; } U;                               \
      U.h = xi - xj;                                                      \
      U.u4[0] &= 0x7FFF7FFFu; U.u4[1] &= 0x7FFF7FFFu;                     \
      U.u4[2] &= 0x7FFF7FFFu; U.u4[3] &= 0x7FFF7FFFu;                     \
      sA[buf][st][w][L] = U.h;                                            \
    }

  #define CONSUME_BODY(kt, buf, st, CEXPR)                                \
    {                                                                     \
      half8 afr[4];                                                       \
      _Pragma("unroll")                                                   \
      for (int s = 0; s < 4; ++s) afr[s] = sA[buf][st][s][L];             \
      half8 bfr[4];                                                       \
      _Pragma("unroll")                                                   \
      for (int u = 0; u < 4; ++u)                                         \
        bfr[u] = *(const half8*)(bbase + (kt) * 8192 + u * 128);          \
      _Pragma("unroll")                                                   \
      for (int s = 0; s < 4; ++s)                                         \
        _Pragma("unroll")                                                 \
        for (int u = 0; u < 4; ++u)                                       \
          acc[s][u] = __builtin_amdgcn_mfma_f32_16x16x32_f16(             \
              afr[s], bfr[u], CEXPR, 0, 0, 0);                            \
    }

  #define CONSUME(kt, buf, st)  CONSUME_BODY(kt, buf, st, acc[s][u])
  #define CONSUME0(kt, buf, st) CONSUME_BODY(kt, buf, st, ((f32x4){0.f, 0.f, 0.f, 0.f}))

  // prologue: chunk 0 (steps 0,1)
  CONSTRUCT(0, 0, 0)
  CONSTRUCT(1, 0, 1)
  BAR();

  // t=0 peeled: step-0 MFMA starts accumulators from literal 0
  CONSUME0(0, 0, 0)
  CONSUME(1, 0, 1)
  CONSTRUCT(2, 1, 0)
  CONSTRUCT(3, 1, 1)
  BAR();

  #pragma unroll 2
  for (int t = 1; t < 8; ++t) {
    const int buf = t & 1;
    CONSUME(2 * t, buf, 0)
    CONSUME(2 * t + 1, buf, 1)
    if (t < 7) {
      CONSTRUCT(2 * t + 2, 1 - buf, 0)
      CONSTRUCT(2 * t + 3, 1 - buf, 1)
    }
    BAR();
  }
  #undef CONSTRUCT
  #undef CONSUME
  #undef CONSUME0
  #undef CONSUME_BODY

  // ---- 17th k-step: label rank-2 + bias via MFMA ----
  // A[m][512..514] = {lab0[m], lab1[m], 1.0}, zeros elsewhere (koct!=0 lanes all-zero).
  {
    half8 bfr[4];
    #pragma unroll
    for (int u = 0; u < 4; ++u)
      bfr[u] = *(const half8*)(bbase + 16 * 8192 + u * 128);
    #pragma unroll
    for (int s = 0; s < 4; ++s) {
      half8 af = (half8){};
      if (koct == 0) {
        int m = s * 16 + nl;
        af[0] = (_Float16)sLab0[m];
        af[1] = (_Float16)sLab1[m];
        af[2] = (_Float16)1.0f;
      }
      #pragma unroll
      for (int u = 0; u < 4; ++u)
        acc[s][u] = __builtin_amdgcn_mfma_f32_16x16x32_f16(af, bfr[u], acc[s][u], 0, 0, 0);
    }
  }

  // ---- epilogue: fast gelu*W2 accumulate, reduce, sigmoid ----
  const int q = L >> 4;
  float ww2[4];
  #pragma unroll
  for (int u = 0; u < 4; ++u) ww2[u] = W2[w * 64 + u * 16 + nl];
  #pragma unroll
  for (int s = 0; s < 4; ++s) {
    #pragma unroll
    for (int r = 0; r < 4; ++r) {
      int m = s * 16 + q * 4 + r;     // C/D: row = quad*4 + reg
      float v = 0.f;
      #pragma unroll
      for (int u = 0; u < 4; ++u) v = gelu_w2_acc(acc[s][u][r], ww2[u], v);
      v += __shfl_xor(v, 1, 64);
      v += __shfl_xor(v, 2, 64);
      v += __shfl_xor(v, 4, 64);
      v += __shfl_xor(v, 8, 64);       // sum over 16 lanes of the quad
      if (nl == 0) sScore[m * 4 + w] = v;
    }
  }
  BAR();
  if (tid < 64) {
    float s4 = sScore[tid * 4 + 0] + sScore[tid * 4 + 1] + sScore[tid * 4 + 2] +
               sScore[tid * 4 + 3] + b2[0];
    float e = fast_exp2(s4 * -1.4426950408889634f);
    float hsv = fast_rcp(1.0f + e);
    int r = tid >> 3, c = tid & 7;
    out_hs[(size_t)(i0 + r) * BN + (j0 + c)] = hsv;
    if (i0 != j0) {
      // mirror tile: element (j0+r, i0+c) = hsv of pair (i0+c, j0+r) = lane (c*8+r)
      float tv = __shfl(hsv, (c << 3) | r, 64);
      out_hs[(size_t)(j0 + r) * BN + (i0 + c)] = tv;
    }
  }
}

// ---------------- row softmax of adj + TAU*log(hs + EPS) ----------------
__global__ __launch_bounds__(256) void softmax_kernel(const float* __restrict__ adj,
                                                      const float* __restrict__ hs,
                                                      float* __restrict__ out) {
  int i = blockIdx.x, t = threadIdx.x;
  __shared__ float redm[4];
  __shared__ float reds[4];
  const float TAUL2 = TAUF * 0.69314718056f;   // TAU*log(h) = (TAU*ln2)*log2(h)
  float l[4];
  float mx = -1e30f;
  #pragma unroll
  for (int k = 0; k < 4; ++k) {
    int j = t + k * 256;
    float lv = adj[(size_t)i * BN + j] + TAUL2 * __log2f(hs[(size_t)i * BN + j] + EPSF);
    l[k] = lv;
    mx = fmaxf(mx, lv);
  }
  #pragma unroll
  for (int o = 1; o <= 32; o <<= 1) mx = fmaxf(mx, __shfl_xor(mx, o, 64));
  if ((t & 63) == 0) redm[t >> 6] = mx;
  __syncthreads();
  mx = fmaxf(fmaxf(redm[0], redm[1]), fmaxf(redm[2], redm[3]));
  float ex[4];
  float se = 0.f;
  #pragma unroll
  for (int k = 0; k < 4; ++k) { ex[k] = __expf(l[k] - mx); se += ex[k]; }
  #pragma unroll
  for (int o = 1; o <= 32; o <<= 1) se += __shfl_xor(se, o, 64);
  if ((t & 63) == 0) reds[t >> 6] = se;
  __syncthreads();
  se = reds[0] + reds[1] + reds[2] + reds[3];
  float inv = fast_rcp(se);
  #pragma unroll
  for (int k = 0; k < 4; ++k) out[(size_t)i * BN + t + k * 256] = ex[k] * inv;
}

extern "C" void kernel_launch(void* const* d_in, const int* in_sizes, int n_in,
                              void* d_out, int out_size, void* d_ws, size_t ws_size,
                              hipStream_t stream) {
  (void)in_sizes; (void)n_in; (void)out_size; (void)ws_size;
  const float* X   = (const float*)d_in[0];
  const float* lg  = (const float*)d_in[1];
  const float* adj = (const float*)d_in[2];
  const float* W1  = (const float*)d_in[3];
  const float* b1  = (const float*)d_in[4];
  const float* W2  = (const float*)d_in[5];
  const float* b2  = (const float*)d_in[6];
  float* out = (float*)d_out;                       // [0,B^2): adj_refined, [B^2,2B^2): h_scores
  _Float16* w1h = (_Float16*)d_ws;                  // 17*8192 fp16 = 272 KB (16 steps + label/bias step)
  float* oh = (float*)((char*)d_ws + 17 * 8192 * 2);  // 1024*2 f32

  float* out_hs = out + (size_t)BN * BN;

  prep_kernel<<<dim3(FEATN + 8), dim3(256), 0, stream>>>(W1, b1, lg, w1h, oh);
  // lower-triangle tiles only (h_scores is symmetric): 65x128 rectangle folds onto triangle
  gemm_kernel<<<dim3(65, 128), dim3(256), 0, stream>>>(X, w1h, oh, W2, b2, out_hs);
  softmax_kernel<<<dim3(BN), dim3(256), 0, stream>>>(adj, out_hs, out);
}